// Round 7
// baseline (243.933 us; speedup 1.0000x reference)
//
#include <hip/hip_runtime.h>
#include <hip/hip_bf16.h>

#define H_ 96
#define W_ 96
#define HW_ 9216
#define C_ 256
#define B_ 2
#define KO_ 27
#define EPS_ 1e-5f

typedef unsigned short u16;
typedef unsigned short ushort8 __attribute__((ext_vector_type(8)));
typedef short short8v __attribute__((ext_vector_type(8)));
typedef float float4v __attribute__((ext_vector_type(4)));

__device__ __forceinline__ float b2f(u16 u) {
    return __uint_as_float(((unsigned int)u) << 16);
}
__device__ __forceinline__ u16 f2b(float f) {
    __hip_bfloat16 h = __float2bfloat16(f);
    union { __hip_bfloat16 h; u16 u; } cv; cv.h = h; return cv.u;
}
__device__ __forceinline__ unsigned int pack2(float a, float b) {
    union { __hip_bfloat162 h; unsigned int u; } cv;
    cv.h = __float22bfloat162_rn(make_float2(a, b));
    return cv.u;
}

// ---------------- kernel 1: weight repacks + BN fold -------
// WQ[((tap*8+cg)*256+o)*32+cp] = bf16(w_conv[o][c][tap]),  c = cg*32+cp
// WO[(tap*8+cg)*1024 + o*32 + cp] = bf16(w_off[o][c][tap]) (o<27, else 0)
__global__ __launch_bounds__(256) void prep_w_kernel(
    const float* __restrict__ w_conv, const float* __restrict__ w_off,
    const float* __restrict__ b_conv,
    const float* __restrict__ gamma, const float* __restrict__ beta,
    const float* __restrict__ rmean, const float* __restrict__ rvar,
    float* __restrict__ AB, u16* __restrict__ WQ, u16* __restrict__ WO)
{
    if (blockIdx.x == 0) {
        int o = threadIdx.x;
        float sc = gamma[o] * rsqrtf(rvar[o] + EPS_);
        AB[o] = sc;
        AB[256 + o] = beta[o] + (b_conv[o] - rmean[o]) * sc;
    }
    if (blockIdx.x < 2304) {
        int idx = blockIdx.x * 256 + threadIdx.x;   // 589824 total
        int ch = idx >> 13;          // chunk = tap*8 + c/32
        int o  = (idx >> 5) & 255;
        int cp = idx & 31;
        int c  = ((ch & 7) << 5) + cp;
        int k  = ch >> 3;
        WQ[idx] = f2b(w_conv[(o * C_ + c) * 9 + k]);
    } else {
        int j = (blockIdx.x - 2304) * 256 + threadIdx.x;  // 73728 total
        int ch = j >> 10;
        int o  = (j >> 5) & 31;
        int cp = j & 31;
        int c  = ((ch & 7) << 5) + cp;
        int k  = ch >> 3;
        WO[j] = (o < KO_) ? f2b(w_off[(o * C_ + c) * 9 + k]) : (u16)0;
    }
}

// ---------------- kernel 2: x NCHW f32 -> NHWC bf16 ----------------
__global__ __launch_bounds__(256) void xt_kernel(const float* __restrict__ x,
                                                 u16* __restrict__ XT)
{
    __shared__ u16 ls[32][100];
    int h  = blockIdx.x;
    int cg = blockIdx.y & 7;
    int b  = blockIdx.y >> 3;
    int c0 = cg * 32;
    for (int e = threadIdx.x; e < 32 * W_; e += 256) {
        int ci = e / W_, w = e % W_;
        ls[ci][w] = f2b(x[((b * C_ + c0 + ci) * H_ + h) * W_ + w]);
    }
    __syncthreads();
    for (int e = threadIdx.x; e < 32 * W_; e += 256) {
        int w = e >> 5, ci = e & 31;
        XT[((b * H_ + h) * W_ + w) * C_ + c0 + ci] = ls[ci][w];
    }
}

// ---------------- kernel 3: offsets (MFMA, K-split across waves) + lerp -> S --
__global__ __launch_bounds__(256) void off_lerp_kernel(
    const u16* __restrict__ XT, const u16* __restrict__ WO,
    const float* __restrict__ b_off, u16* __restrict__ S)
{
    __shared__ float red[4][32][16];
    __shared__ float offv[27][16];

    const int tid = threadIdx.x;
    const int b  = blockIdx.y;
    const int p0 = blockIdx.x * 16;
    const int h  = p0 / W_;            // 16 px all on one row
    const int w0 = p0 % W_;

    const int wave = tid >> 6;
    const int lane = tid & 63;
    const int quad = lane >> 4;
    const int l15  = lane & 15;

    // ---- phase 1 ----
    {
        const int pw = w0 + l15;
        float4v acc0 = float4v{0.f,0.f,0.f,0.f};
        float4v acc1 = float4v{0.f,0.f,0.f,0.f};
        int basec = 0; bool vld = true; int curtap = -1;
        auto set_tap = [&](int tap) {
            int py  = h + tap / 3 - 1;
            int pxl = pw + tap % 3 - 1;
            vld = ((unsigned)py < (unsigned)H_) && ((unsigned)pxl < (unsigned)W_);
            int pyc = min(max(py, 0), H_ - 1);
            int pxc = min(max(pxl, 0), W_ - 1);
            basec = ((b * H_ + pyc) * W_ + pxc) * C_ + quad * 8;
        };
        auto bload = [&](int c32) -> ushort8 {
            ushort8 v = *(const ushort8*)(XT + basec + (c32 & 7) * 32);
#pragma unroll
            for (int j = 0; j < 8; j++) v[j] = vld ? v[j] : (u16)0;
            return v;
        };
        const int c0 = wave * 18, c1 = c0 + 18;
        curtap = c0 >> 3;
        set_tap(curtap);
        ushort8 bq = bload(c0);
        short8v wa = *(const short8v*)(WO + c0 * 1024 + l15 * 32 + quad * 8);
        short8v wb = *(const short8v*)(WO + c0 * 1024 + l15 * 32 + quad * 8 + 512);
        for (int i = c0; i < c1; ++i) {
            ushort8 bc = bq;
            short8v wac = wa, wbc = wb;
            int nx = i + 1;
            if (nx < c1) {
                int t = nx >> 3;
                if (t != curtap) { set_tap(t); curtap = t; }
                bq = bload(nx);
                wa = *(const short8v*)(WO + nx * 1024 + l15 * 32 + quad * 8);
                wb = *(const short8v*)(WO + nx * 1024 + l15 * 32 + quad * 8 + 512);
            }
            union { ushort8 u; short8v s; } cb; cb.u = bc;
            acc0 = __builtin_amdgcn_mfma_f32_16x16x32_bf16(wac, cb.s, acc0, 0, 0, 0);
            acc1 = __builtin_amdgcn_mfma_f32_16x16x32_bf16(wbc, cb.s, acc1, 0, 0, 0);
        }
#pragma unroll
        for (int r = 0; r < 4; ++r) {
            red[wave][quad * 4 + r][l15]      = acc0[r];
            red[wave][16 + quad * 4 + r][l15] = acc1[r];
        }
    }
    __syncthreads();
#pragma unroll
    for (int rep = 0; rep < 2; ++rep) {
        int o  = (tid >> 4) + rep * 16;   // 0..31
        int px = tid & 15;
        if (o < KO_) {
            float v = red[0][o][px] + red[1][o][px] + red[2][o][px] + red[3][o][px]
                    + b_off[o];
            offv[o][px] = (o < 18) ? v : 1.f / (1.f + expf(-v));
        }
    }
    __syncthreads();

    // ---- phase 2: gather + lerp -> S ----
    const int px = tid >> 4;      // 0..15
    const int j  = tid & 15;      // ch-lane
    const int pw2 = w0 + px;
    const int pix = h * W_ + pw2;
    u16* srow = S + (size_t)(b * HW_ + pix) * 2304;

    for (int tap = 0; tap < 9; ++tap) {
        float dy = offv[2 * tap][px];
        float dx = offv[2 * tap + 1][px];
        float m  = offv[18 + tap][px];
        float py  = (float)(h + tap / 3 - 1) + dy;
        float pxx = (float)(pw2 + tap % 3 - 1) + dx;
        float y0f = floorf(py), x0f = floorf(pxx);
        float ly = py - y0f, lx = pxx - x0f;
        int y0 = (int)y0f, x0i = (int)x0f;
        int y1 = y0 + 1, x1 = x0i + 1;
        bool vy0 = (unsigned)y0 < (unsigned)H_;
        bool vy1 = (unsigned)y1 < (unsigned)H_;
        bool vx0 = (unsigned)x0i < (unsigned)W_;
        bool vx1 = (unsigned)x1 < (unsigned)W_;
        float fw0 = (vy0 && vx0) ? (1.f - ly) * (1.f - lx) * m : 0.f;
        float fw1 = (vy0 && vx1) ? (1.f - ly) * lx * m : 0.f;
        float fw2 = (vy1 && vx0) ? ly * (1.f - lx) * m : 0.f;
        float fw3 = (vy1 && vx1) ? ly * lx * m : 0.f;
        int y0c = min(max(y0, 0), H_ - 1), y1c = min(max(y1, 0), H_ - 1);
        int x0c = min(max(x0i, 0), W_ - 1), x1c = min(max(x1, 0), W_ - 1);
        int a00 = ((b * H_ + y0c) * W_ + x0c) * C_;
        int a01 = ((b * H_ + y0c) * W_ + x1c) * C_;
        int a10 = ((b * H_ + y1c) * W_ + x0c) * C_;
        int a11 = ((b * H_ + y1c) * W_ + x1c) * C_;
#pragma unroll
        for (int cc = 0; cc < 2; ++cc) {
            int ch = cc * 128 + j * 8;
            ushort8 v00 = *(const ushort8*)(XT + a00 + ch);
            ushort8 v01 = *(const ushort8*)(XT + a01 + ch);
            ushort8 v10 = *(const ushort8*)(XT + a10 + ch);
            ushort8 v11 = *(const ushort8*)(XT + a11 + ch);
            float v[8];
#pragma unroll
            for (int t = 0; t < 8; t++)
                v[t] = fw0 * b2f(v00[t]) + fw1 * b2f(v01[t])
                     + fw2 * b2f(v10[t]) + fw3 * b2f(v11[t]);
            uint4 sv;
            sv.x = pack2(v[0], v[1]);
            sv.y = pack2(v[2], v[3]);
            sv.z = pack2(v[4], v[5]);
            sv.w = pack2(v[6], v[7]);
            *(uint4*)(srow + tap * 256 + ch) = sv;
        }
    }
}

// ---------------- kernel 4: GEMM out = relu(BN(W*S)) + x ----------------
// Barrier-free, LDS-free. Block = 4 waves; wave w owns o-tile [w*64, w*64+64),
// all waves share px range [n0, n0+64). A direct from WQ (L2), B direct from
// S, depth-2 chunk64 register pipeline -> fine-grained vmcnt waits.
// K = 2304 = 36 chunk64s (was 18 in round 6 -- the bug).
__global__ __launch_bounds__(256) void gemm_kernel(
    const float* __restrict__ x, const u16* __restrict__ S,
    const u16* __restrict__ WQ, const float* __restrict__ AB,
    float* __restrict__ out)
{
    const int tid = threadIdx.x;
    const int wave = tid >> 6;
    const int lane = tid & 63;
    const int quad = lane >> 4;
    const int l15  = lane & 15;

    const int n0 = blockIdx.x * 64;      // global px index (b*HW + pix)
    const int o0 = wave * 64;

    const u16* srow  = S + (size_t)(n0 + l15) * 2304 + quad * 8;
    const u16* wbase = WQ + (o0 + l15) * 32 + quad * 8;

    float4v acc[4][4];
#pragma unroll
    for (int i = 0; i < 4; i++)
#pragma unroll
        for (int j = 0; j < 4; j++)
            acc[i][j] = float4v{0.f, 0.f, 0.f, 0.f};

    short8v aA[2][4], aB[2][4];      // double-buffered A [ks][mt]
    short8v bA[2][4], bB[2][4];      // double-buffered B [ks][nt]

    auto load_a = [&](int ch64, short8v A[2][4]) {
#pragma unroll
        for (int ks = 0; ks < 2; ++ks) {
            const u16* p = wbase + (size_t)(ch64 * 2 + ks) * 8192;
#pragma unroll
            for (int mt = 0; mt < 4; ++mt)
                A[ks][mt] = *(const short8v*)(p + mt * 512);
        }
    };
    auto load_b = [&](int ch64, short8v Bv[2][4]) {
#pragma unroll
        for (int ks = 0; ks < 2; ++ks) {
            const int ko = (ch64 * 2 + ks) * 32;
#pragma unroll
            for (int nt = 0; nt < 4; ++nt)
                Bv[ks][nt] = *(const short8v*)(srow + (size_t)nt * 16 * 2304 + ko);
        }
    };
    auto domfma = [&](short8v A[2][4], short8v Bv[2][4]) {
#pragma unroll
        for (int ks = 0; ks < 2; ++ks)
#pragma unroll
            for (int mt = 0; mt < 4; ++mt)
#pragma unroll
                for (int nt = 0; nt < 4; ++nt)
                    acc[mt][nt] = __builtin_amdgcn_mfma_f32_16x16x32_bf16(
                        A[ks][mt], Bv[ks][nt], acc[mt][nt], 0, 0, 0);
    };

    load_a(0, aA); load_b(0, bA);
    // 36 chunk64 iterations, manually unrolled x2 for register double-buffering
    for (int ch = 0; ch < 36; ch += 2) {
        if (ch + 1 < 36) { load_a(ch + 1, aB); load_b(ch + 1, bB); }
        domfma(aA, bA);
        if (ch + 2 < 36) { load_a(ch + 2, aA); load_b(ch + 2, bA); }
        domfma(aB, bB);
    }

    // epilogue: BN fold + relu + residual
    const float* Ao = AB;
    const float* Bo = AB + 256;
    const int b   = n0 / HW_;            // block never straddles batch
    const int pix0 = n0 - b * HW_;
#pragma unroll
    for (int mt = 0; mt < 4; mt++) {
#pragma unroll
        for (int nt = 0; nt < 4; nt++) {
            int pix = pix0 + nt * 16 + l15;
#pragma unroll
            for (int r = 0; r < 4; r++) {
                int o = o0 + mt * 16 + quad * 4 + r;
                float v = acc[mt][nt][r] * Ao[o] + Bo[o];
                v = fmaxf(v, 0.f);
                int gi = (b * C_ + o) * HW_ + pix;
                out[gi] = x[gi] + v;
            }
        }
    }
}

extern "C" void kernel_launch(void* const* d_in, const int* in_sizes, int n_in,
                              void* d_out, int out_size, void* d_ws, size_t ws_size,
                              hipStream_t stream)
{
    (void)in_sizes; (void)n_in; (void)out_size; (void)ws_size;
    const float* x      = (const float*)d_in[0];
    const float* w_off  = (const float*)d_in[1];
    const float* b_off  = (const float*)d_in[2];
    const float* w_conv = (const float*)d_in[3];
    const float* b_conv = (const float*)d_in[4];
    const float* gamma  = (const float*)d_in[5];
    const float* beta   = (const float*)d_in[6];
    const float* rmean  = (const float*)d_in[7];
    const float* rvar   = (const float*)d_in[8];
    float* out = (float*)d_out;

    float* ws = (float*)d_ws;
    float* AB = ws;                            // 512 floats
    u16* WQ = (u16*)(AB + 512);                // 589824
    u16* WO = WQ + 589824;                     // 73728
    u16* XT = WO + 73728;                      // 4718592
    u16* S  = XT + 4718592;                    // 2*9216*2304 = 42467328

    prep_w_kernel<<<2592, 256, 0, stream>>>(w_conv, w_off, b_conv, gamma, beta,
                                            rmean, rvar, AB, WQ, WO);
    xt_kernel<<<dim3(96, 16), 256, 0, stream>>>(x, XT);
    off_lerp_kernel<<<dim3(576, 2), 256, 0, stream>>>(XT, WO, b_off, S);
    gemm_kernel<<<288, 256, 0, stream>>>(x, S, WQ, AB, out);
}

// Round 8
// 238.558 us; speedup vs baseline: 1.0225x; 1.0225x over previous
//
#include <hip/hip_runtime.h>
#include <hip/hip_bf16.h>

#define H_ 96
#define W_ 96
#define HW_ 9216
#define C_ 256
#define B_ 2
#define KO_ 27
#define EPS_ 1e-5f

typedef unsigned short u16;
typedef unsigned short ushort8 __attribute__((ext_vector_type(8)));
typedef short short8v __attribute__((ext_vector_type(8)));
typedef float float4v __attribute__((ext_vector_type(4)));

__device__ __forceinline__ float b2f(u16 u) {
    return __uint_as_float(((unsigned int)u) << 16);
}
__device__ __forceinline__ u16 f2b(float f) {
    __hip_bfloat16 h = __float2bfloat16(f);
    union { __hip_bfloat16 h; u16 u; } cv; cv.h = h; return cv.u;
}
__device__ __forceinline__ unsigned int pack2(float a, float b) {
    union { __hip_bfloat162 h; unsigned int u; } cv;
    cv.h = __float22bfloat162_rn(make_float2(a, b));
    return cv.u;
}

// ---------------- kernel 1: weight repacks + BN fold -------
// WQ[((tap*8+cg)*256+o)*32+cp] = bf16(w_conv[o][c][tap]),  c = cg*32+cp
// WO[(tap*8+cg)*1024 + o*32 + cp] = bf16(w_off[o][c][tap]) (o<27, else 0)
__global__ __launch_bounds__(256) void prep_w_kernel(
    const float* __restrict__ w_conv, const float* __restrict__ w_off,
    const float* __restrict__ b_conv,
    const float* __restrict__ gamma, const float* __restrict__ beta,
    const float* __restrict__ rmean, const float* __restrict__ rvar,
    float* __restrict__ AB, u16* __restrict__ WQ, u16* __restrict__ WO)
{
    if (blockIdx.x == 0) {
        int o = threadIdx.x;
        float sc = gamma[o] * rsqrtf(rvar[o] + EPS_);
        AB[o] = sc;
        AB[256 + o] = beta[o] + (b_conv[o] - rmean[o]) * sc;
    }
    if (blockIdx.x < 2304) {
        int idx = blockIdx.x * 256 + threadIdx.x;   // 589824 total
        int ch = idx >> 13;          // chunk = tap*8 + c/32
        int o  = (idx >> 5) & 255;
        int cp = idx & 31;
        int c  = ((ch & 7) << 5) + cp;
        int k  = ch >> 3;
        WQ[idx] = f2b(w_conv[(o * C_ + c) * 9 + k]);
    } else {
        int j = (blockIdx.x - 2304) * 256 + threadIdx.x;  // 73728 total
        int ch = j >> 10;
        int o  = (j >> 5) & 31;
        int cp = j & 31;
        int c  = ((ch & 7) << 5) + cp;
        int k  = ch >> 3;
        WO[j] = (o < KO_) ? f2b(w_off[(o * C_ + c) * 9 + k]) : (u16)0;
    }
}

// ---------------- kernel 2: x NCHW f32 -> NHWC bf16 ----------------
__global__ __launch_bounds__(256) void xt_kernel(const float* __restrict__ x,
                                                 u16* __restrict__ XT)
{
    __shared__ u16 ls[32][100];
    int h  = blockIdx.x;
    int cg = blockIdx.y & 7;
    int b  = blockIdx.y >> 3;
    int c0 = cg * 32;
    for (int e = threadIdx.x; e < 32 * W_; e += 256) {
        int ci = e / W_, w = e % W_;
        ls[ci][w] = f2b(x[((b * C_ + c0 + ci) * H_ + h) * W_ + w]);
    }
    __syncthreads();
    for (int e = threadIdx.x; e < 32 * W_; e += 256) {
        int w = e >> 5, ci = e & 31;
        XT[((b * H_ + h) * W_ + w) * C_ + c0 + ci] = ls[ci][w];
    }
}

// ---------------- kernel 3: offsets (MFMA, K-split across waves) + lerp -> S --
__global__ __launch_bounds__(256) void off_lerp_kernel(
    const u16* __restrict__ XT, const u16* __restrict__ WO,
    const float* __restrict__ b_off, u16* __restrict__ S)
{
    __shared__ float red[4][32][16];
    __shared__ float offv[27][16];

    const int tid = threadIdx.x;
    const int b  = blockIdx.y;
    const int p0 = blockIdx.x * 16;
    const int h  = p0 / W_;            // 16 px all on one row
    const int w0 = p0 % W_;

    const int wave = tid >> 6;
    const int lane = tid & 63;
    const int quad = lane >> 4;
    const int l15  = lane & 15;

    // ---- phase 1 ----
    {
        const int pw = w0 + l15;
        float4v acc0 = float4v{0.f,0.f,0.f,0.f};
        float4v acc1 = float4v{0.f,0.f,0.f,0.f};
        int basec = 0; bool vld = true; int curtap = -1;
        auto set_tap = [&](int tap) {
            int py  = h + tap / 3 - 1;
            int pxl = pw + tap % 3 - 1;
            vld = ((unsigned)py < (unsigned)H_) && ((unsigned)pxl < (unsigned)W_);
            int pyc = min(max(py, 0), H_ - 1);
            int pxc = min(max(pxl, 0), W_ - 1);
            basec = ((b * H_ + pyc) * W_ + pxc) * C_ + quad * 8;
        };
        auto bload = [&](int c32) -> ushort8 {
            ushort8 v = *(const ushort8*)(XT + basec + (c32 & 7) * 32);
#pragma unroll
            for (int j = 0; j < 8; j++) v[j] = vld ? v[j] : (u16)0;
            return v;
        };
        const int c0 = wave * 18, c1 = c0 + 18;
        curtap = c0 >> 3;
        set_tap(curtap);
        ushort8 bq = bload(c0);
        short8v wa = *(const short8v*)(WO + c0 * 1024 + l15 * 32 + quad * 8);
        short8v wb = *(const short8v*)(WO + c0 * 1024 + l15 * 32 + quad * 8 + 512);
        for (int i = c0; i < c1; ++i) {
            ushort8 bc = bq;
            short8v wac = wa, wbc = wb;
            int nx = i + 1;
            if (nx < c1) {
                int t = nx >> 3;
                if (t != curtap) { set_tap(t); curtap = t; }
                bq = bload(nx);
                wa = *(const short8v*)(WO + nx * 1024 + l15 * 32 + quad * 8);
                wb = *(const short8v*)(WO + nx * 1024 + l15 * 32 + quad * 8 + 512);
            }
            union { ushort8 u; short8v s; } cb; cb.u = bc;
            acc0 = __builtin_amdgcn_mfma_f32_16x16x32_bf16(wac, cb.s, acc0, 0, 0, 0);
            acc1 = __builtin_amdgcn_mfma_f32_16x16x32_bf16(wbc, cb.s, acc1, 0, 0, 0);
        }
#pragma unroll
        for (int r = 0; r < 4; ++r) {
            red[wave][quad * 4 + r][l15]      = acc0[r];
            red[wave][16 + quad * 4 + r][l15] = acc1[r];
        }
    }
    __syncthreads();
#pragma unroll
    for (int rep = 0; rep < 2; ++rep) {
        int o  = (tid >> 4) + rep * 16;   // 0..31
        int px = tid & 15;
        if (o < KO_) {
            float v = red[0][o][px] + red[1][o][px] + red[2][o][px] + red[3][o][px]
                    + b_off[o];
            offv[o][px] = (o < 18) ? v : 1.f / (1.f + expf(-v));
        }
    }
    __syncthreads();

    // ---- phase 2: gather + lerp -> S ----
    const int px = tid >> 4;      // 0..15
    const int j  = tid & 15;      // ch-lane
    const int pw2 = w0 + px;
    const int pix = h * W_ + pw2;
    u16* srow = S + (size_t)(b * HW_ + pix) * 2304;

    for (int tap = 0; tap < 9; ++tap) {
        float dy = offv[2 * tap][px];
        float dx = offv[2 * tap + 1][px];
        float m  = offv[18 + tap][px];
        float py  = (float)(h + tap / 3 - 1) + dy;
        float pxx = (float)(pw2 + tap % 3 - 1) + dx;
        float y0f = floorf(py), x0f = floorf(pxx);
        float ly = py - y0f, lx = pxx - x0f;
        int y0 = (int)y0f, x0i = (int)x0f;
        int y1 = y0 + 1, x1 = x0i + 1;
        bool vy0 = (unsigned)y0 < (unsigned)H_;
        bool vy1 = (unsigned)y1 < (unsigned)H_;
        bool vx0 = (unsigned)x0i < (unsigned)W_;
        bool vx1 = (unsigned)x1 < (unsigned)W_;
        float fw0 = (vy0 && vx0) ? (1.f - ly) * (1.f - lx) * m : 0.f;
        float fw1 = (vy0 && vx1) ? (1.f - ly) * lx * m : 0.f;
        float fw2 = (vy1 && vx0) ? ly * (1.f - lx) * m : 0.f;
        float fw3 = (vy1 && vx1) ? ly * lx * m : 0.f;
        int y0c = min(max(y0, 0), H_ - 1), y1c = min(max(y1, 0), H_ - 1);
        int x0c = min(max(x0i, 0), W_ - 1), x1c = min(max(x1, 0), W_ - 1);
        int a00 = ((b * H_ + y0c) * W_ + x0c) * C_;
        int a01 = ((b * H_ + y0c) * W_ + x1c) * C_;
        int a10 = ((b * H_ + y1c) * W_ + x0c) * C_;
        int a11 = ((b * H_ + y1c) * W_ + x1c) * C_;
#pragma unroll
        for (int cc = 0; cc < 2; ++cc) {
            int ch = cc * 128 + j * 8;
            ushort8 v00 = *(const ushort8*)(XT + a00 + ch);
            ushort8 v01 = *(const ushort8*)(XT + a01 + ch);
            ushort8 v10 = *(const ushort8*)(XT + a10 + ch);
            ushort8 v11 = *(const ushort8*)(XT + a11 + ch);
            float v[8];
#pragma unroll
            for (int t = 0; t < 8; t++)
                v[t] = fw0 * b2f(v00[t]) + fw1 * b2f(v01[t])
                     + fw2 * b2f(v10[t]) + fw3 * b2f(v11[t]);
            uint4 sv;
            sv.x = pack2(v[0], v[1]);
            sv.y = pack2(v[2], v[3]);
            sv.z = pack2(v[4], v[5]);
            sv.w = pack2(v[6], v[7]);
            *(uint4*)(srow + tap * 256 + ch) = sv;
        }
    }
}

// ---------------- kernel 4: GEMM out = relu(BN(W*S)) + x ----------------
// Barrier-free, LDS-free. Wave tile 64o x 32px (fits registers: acc 32 +
// A-bufs 64 + B-bufs 32 VGPR). Block = 4 waves -> 256o x 32px. Grid 576.
__global__ __launch_bounds__(256, 2) void gemm_kernel(
    const float* __restrict__ x, const u16* __restrict__ S,
    const u16* __restrict__ WQ, const float* __restrict__ AB,
    float* __restrict__ out)
{
    const int tid = threadIdx.x;
    const int wave = tid >> 6;
    const int lane = tid & 63;
    const int quad = lane >> 4;
    const int l15  = lane & 15;

    const int n0 = blockIdx.x * 32;      // global px index (b*HW + pix)
    const int o0 = wave * 64;

    const u16* srow  = S + (size_t)(n0 + l15) * 2304 + quad * 8;
    const u16* wbase = WQ + (o0 + l15) * 32 + quad * 8;

    float4v acc[4][2];
#pragma unroll
    for (int i = 0; i < 4; i++)
#pragma unroll
        for (int j = 0; j < 2; j++)
            acc[i][j] = float4v{0.f, 0.f, 0.f, 0.f};

    short8v aA[2][4], aB[2][4];      // double-buffered A [ks][mt]
    short8v bA[2][2], bB[2][2];      // double-buffered B [ks][nt]

    auto load_a = [&](int ch64, short8v A[2][4]) {
#pragma unroll
        for (int ks = 0; ks < 2; ++ks) {
            const u16* p = wbase + (size_t)(ch64 * 2 + ks) * 8192;
#pragma unroll
            for (int mt = 0; mt < 4; ++mt)
                A[ks][mt] = *(const short8v*)(p + mt * 512);
        }
    };
    auto load_b = [&](int ch64, short8v Bv[2][2]) {
#pragma unroll
        for (int ks = 0; ks < 2; ++ks) {
            const int ko = (ch64 * 2 + ks) * 32;
#pragma unroll
            for (int nt = 0; nt < 2; ++nt)
                Bv[ks][nt] = *(const short8v*)(srow + (size_t)nt * 16 * 2304 + ko);
        }
    };
    auto domfma = [&](short8v A[2][4], short8v Bv[2][2]) {
#pragma unroll
        for (int ks = 0; ks < 2; ++ks)
#pragma unroll
            for (int mt = 0; mt < 4; ++mt)
#pragma unroll
                for (int nt = 0; nt < 2; ++nt)
                    acc[mt][nt] = __builtin_amdgcn_mfma_f32_16x16x32_bf16(
                        A[ks][mt], Bv[ks][nt], acc[mt][nt], 0, 0, 0);
    };

    load_a(0, aA); load_b(0, bA);
    // 36 chunk64 iterations, manually unrolled x2 for register double-buffering
    for (int ch = 0; ch < 36; ch += 2) {
        if (ch + 1 < 36) { load_a(ch + 1, aB); load_b(ch + 1, bB); }
        domfma(aA, bA);
        if (ch + 2 < 36) { load_a(ch + 2, aA); load_b(ch + 2, bA); }
        domfma(aB, bB);
    }

    // epilogue: BN fold + relu + residual
    const float* Ao = AB;
    const float* Bo = AB + 256;
    const int b   = n0 / HW_;            // block never straddles batch
    const int pix0 = n0 - b * HW_;
#pragma unroll
    for (int mt = 0; mt < 4; mt++) {
#pragma unroll
        for (int nt = 0; nt < 2; nt++) {
            int pix = pix0 + nt * 16 + l15;
#pragma unroll
            for (int r = 0; r < 4; r++) {
                int o = o0 + mt * 16 + quad * 4 + r;
                float v = acc[mt][nt][r] * Ao[o] + Bo[o];
                v = fmaxf(v, 0.f);
                int gi = (b * C_ + o) * HW_ + pix;
                out[gi] = x[gi] + v;
            }
        }
    }
}

extern "C" void kernel_launch(void* const* d_in, const int* in_sizes, int n_in,
                              void* d_out, int out_size, void* d_ws, size_t ws_size,
                              hipStream_t stream)
{
    (void)in_sizes; (void)n_in; (void)out_size; (void)ws_size;
    const float* x      = (const float*)d_in[0];
    const float* w_off  = (const float*)d_in[1];
    const float* b_off  = (const float*)d_in[2];
    const float* w_conv = (const float*)d_in[3];
    const float* b_conv = (const float*)d_in[4];
    const float* gamma  = (const float*)d_in[5];
    const float* beta   = (const float*)d_in[6];
    const float* rmean  = (const float*)d_in[7];
    const float* rvar   = (const float*)d_in[8];
    float* out = (float*)d_out;

    float* ws = (float*)d_ws;
    float* AB = ws;                            // 512 floats
    u16* WQ = (u16*)(AB + 512);                // 589824
    u16* WO = WQ + 589824;                     // 73728
    u16* XT = WO + 73728;                      // 4718592
    u16* S  = XT + 4718592;                    // 2*9216*2304 = 42467328

    prep_w_kernel<<<2592, 256, 0, stream>>>(w_conv, w_off, b_conv, gamma, beta,
                                            rmean, rvar, AB, WQ, WO);
    xt_kernel<<<dim3(96, 16), 256, 0, stream>>>(x, XT);
    off_lerp_kernel<<<dim3(576, 2), 256, 0, stream>>>(XT, WO, b_off, S);
    gemm_kernel<<<576, 256, 0, stream>>>(x, S, WQ, AB, out);
}

// Round 9
// 220.149 us; speedup vs baseline: 1.1080x; 1.0836x over previous
//
#include <hip/hip_runtime.h>
#include <hip/hip_bf16.h>

#define H_ 96
#define W_ 96
#define HW_ 9216
#define C_ 256
#define B_ 2
#define KO_ 27
#define NPX_ 18432   // B*HW
#define EPS_ 1e-5f

typedef unsigned short u16;
typedef unsigned short ushort8 __attribute__((ext_vector_type(8)));
typedef short short8v __attribute__((ext_vector_type(8)));
typedef float float4v __attribute__((ext_vector_type(4)));

__device__ __forceinline__ float b2f(u16 u) {
    return __uint_as_float(((unsigned int)u) << 16);
}
__device__ __forceinline__ u16 f2b(float f) {
    __hip_bfloat16 h = __float2bfloat16(f);
    union { __hip_bfloat16 h; u16 u; } cv; cv.h = h; return cv.u;
}
__device__ __forceinline__ unsigned int pack2(float a, float b) {
    union { __hip_bfloat162 h; unsigned int u; } cv;
    cv.h = __float22bfloat162_rn(make_float2(a, b));
    return cv.u;
}

// ---------------- kernel 1: weight repacks + BN fold -------
// WQ[((tap*8+cg)*256+o)*32+cp] = bf16(w_conv[o][c][tap]),  c = cg*32+cp
// WO[(tap*8+cg)*1024 + o*32 + cp] = bf16(w_off[o][c][tap]) (o<27, else 0)
__global__ __launch_bounds__(256) void prep_w_kernel(
    const float* __restrict__ w_conv, const float* __restrict__ w_off,
    const float* __restrict__ b_conv,
    const float* __restrict__ gamma, const float* __restrict__ beta,
    const float* __restrict__ rmean, const float* __restrict__ rvar,
    float* __restrict__ AB, u16* __restrict__ WQ, u16* __restrict__ WO)
{
    if (blockIdx.x == 0) {
        int o = threadIdx.x;
        float sc = gamma[o] * rsqrtf(rvar[o] + EPS_);
        AB[o] = sc;
        AB[256 + o] = beta[o] + (b_conv[o] - rmean[o]) * sc;
    }
    if (blockIdx.x < 2304) {
        int idx = blockIdx.x * 256 + threadIdx.x;   // 589824 total
        int ch = idx >> 13;          // chunk = tap*8 + c/32
        int o  = (idx >> 5) & 255;
        int cp = idx & 31;
        int c  = ((ch & 7) << 5) + cp;
        int k  = ch >> 3;
        WQ[idx] = f2b(w_conv[(o * C_ + c) * 9 + k]);
    } else {
        int j = (blockIdx.x - 2304) * 256 + threadIdx.x;  // 73728 total
        int ch = j >> 10;
        int o  = (j >> 5) & 31;
        int cp = j & 31;
        int c  = ((ch & 7) << 5) + cp;
        int k  = ch >> 3;
        WO[j] = (o < KO_) ? f2b(w_off[(o * C_ + c) * 9 + k]) : (u16)0;
    }
}

// ---------------- kernel 2: x NCHW f32 -> NHWC bf16 ----------------
__global__ __launch_bounds__(256) void xt_kernel(const float* __restrict__ x,
                                                 u16* __restrict__ XT)
{
    __shared__ u16 ls[32][100];
    int h  = blockIdx.x;
    int cg = blockIdx.y & 7;
    int b  = blockIdx.y >> 3;
    int c0 = cg * 32;
    for (int e = threadIdx.x; e < 32 * W_; e += 256) {
        int ci = e / W_, w = e % W_;
        ls[ci][w] = f2b(x[((b * C_ + c0 + ci) * H_ + h) * W_ + w]);
    }
    __syncthreads();
    for (int e = threadIdx.x; e < 32 * W_; e += 256) {
        int w = e >> 5, ci = e & 31;
        XT[((b * H_ + h) * W_ + w) * C_ + c0 + ci] = ls[ci][w];
    }
}

// ---------------- kernel 3: offsets (MFMA) + lerp -> SQ (fragment-ordered) --
// SQ[(ch32*NPX + n)*32 + kp] = lerped bf16 for channel c = (ch32&7)*32+kp,
// tap = ch32>>3, pixel n = b*HW + pix.
__global__ __launch_bounds__(256) void off_lerp_kernel(
    const u16* __restrict__ XT, const u16* __restrict__ WO,
    const float* __restrict__ b_off, u16* __restrict__ SQ)
{
    __shared__ float red[4][32][16];
    __shared__ float offv[27][16];
    __shared__ u16 T[16][264];          // [px][c] lerp tile for one tap

    const int tid = threadIdx.x;
    const int b  = blockIdx.y;
    const int p0 = blockIdx.x * 16;
    const int h  = p0 / W_;            // 16 px all on one row
    const int w0 = p0 % W_;

    const int wave = tid >> 6;
    const int lane = tid & 63;
    const int quad = lane >> 4;
    const int l15  = lane & 15;

    // ---- phase 1: 27x2304 offset GEMM, K split across 4 waves ----
    {
        const int pw = w0 + l15;
        float4v acc0 = float4v{0.f,0.f,0.f,0.f};
        float4v acc1 = float4v{0.f,0.f,0.f,0.f};
        int basec = 0; bool vld = true; int curtap = -1;
        auto set_tap = [&](int tap) {
            int py  = h + tap / 3 - 1;
            int pxl = pw + tap % 3 - 1;
            vld = ((unsigned)py < (unsigned)H_) && ((unsigned)pxl < (unsigned)W_);
            int pyc = min(max(py, 0), H_ - 1);
            int pxc = min(max(pxl, 0), W_ - 1);
            basec = ((b * H_ + pyc) * W_ + pxc) * C_ + quad * 8;
        };
        auto bload = [&](int c32) -> ushort8 {
            ushort8 v = *(const ushort8*)(XT + basec + (c32 & 7) * 32);
#pragma unroll
            for (int j = 0; j < 8; j++) v[j] = vld ? v[j] : (u16)0;
            return v;
        };
        const int c0 = wave * 18, c1 = c0 + 18;
        curtap = c0 >> 3;
        set_tap(curtap);
        ushort8 bq = bload(c0);
        short8v wa = *(const short8v*)(WO + c0 * 1024 + l15 * 32 + quad * 8);
        short8v wb = *(const short8v*)(WO + c0 * 1024 + l15 * 32 + quad * 8 + 512);
        for (int i = c0; i < c1; ++i) {
            ushort8 bc = bq;
            short8v wac = wa, wbc = wb;
            int nx = i + 1;
            if (nx < c1) {
                int t = nx >> 3;
                if (t != curtap) { set_tap(t); curtap = t; }
                bq = bload(nx);
                wa = *(const short8v*)(WO + nx * 1024 + l15 * 32 + quad * 8);
                wb = *(const short8v*)(WO + nx * 1024 + l15 * 32 + quad * 8 + 512);
            }
            union { ushort8 u; short8v s; } cb; cb.u = bc;
            acc0 = __builtin_amdgcn_mfma_f32_16x16x32_bf16(wac, cb.s, acc0, 0, 0, 0);
            acc1 = __builtin_amdgcn_mfma_f32_16x16x32_bf16(wbc, cb.s, acc1, 0, 0, 0);
        }
#pragma unroll
        for (int r = 0; r < 4; ++r) {
            red[wave][quad * 4 + r][l15]      = acc0[r];
            red[wave][16 + quad * 4 + r][l15] = acc1[r];
        }
    }
    __syncthreads();
#pragma unroll
    for (int rep = 0; rep < 2; ++rep) {
        int o  = (tid >> 4) + rep * 16;   // 0..31
        int px = tid & 15;
        if (o < KO_) {
            float v = red[0][o][px] + red[1][o][px] + red[2][o][px] + red[3][o][px]
                    + b_off[o];
            offv[o][px] = (o < 18) ? v : 1.f / (1.f + expf(-v));
        }
    }
    __syncthreads();

    // ---- phase 2: gather + lerp -> LDS tile -> coalesced SQ writes ----
    const int px = tid >> 4;      // 0..15
    const int j  = tid & 15;      // ch-lane
    const int pw2 = w0 + px;
    const int n_base = b * HW_ + p0;   // global n of px 0 in this block

    // write-phase mapping (2 units of 16B per thread per tap)
    const int u_cg0   = tid >> 6;            // r=0: cg 0..3
    const int u_in0   = tid & 63;
    const int wpx0    = u_in0 >> 2, kp0 = (u_in0 & 3) * 8;

    for (int tap = 0; tap < 9; ++tap) {
        float dy = offv[2 * tap][px];
        float dx = offv[2 * tap + 1][px];
        float m  = offv[18 + tap][px];
        float py  = (float)(h + tap / 3 - 1) + dy;
        float pxx = (float)(pw2 + tap % 3 - 1) + dx;
        float y0f = floorf(py), x0f = floorf(pxx);
        float ly = py - y0f, lx = pxx - x0f;
        int y0 = (int)y0f, x0i = (int)x0f;
        int y1 = y0 + 1, x1 = x0i + 1;
        bool vy0 = (unsigned)y0 < (unsigned)H_;
        bool vy1 = (unsigned)y1 < (unsigned)H_;
        bool vx0 = (unsigned)x0i < (unsigned)W_;
        bool vx1 = (unsigned)x1 < (unsigned)W_;
        float fw0 = (vy0 && vx0) ? (1.f - ly) * (1.f - lx) * m : 0.f;
        float fw1 = (vy0 && vx1) ? (1.f - ly) * lx * m : 0.f;
        float fw2 = (vy1 && vx0) ? ly * (1.f - lx) * m : 0.f;
        float fw3 = (vy1 && vx1) ? ly * lx * m : 0.f;
        int y0c = min(max(y0, 0), H_ - 1), y1c = min(max(y1, 0), H_ - 1);
        int x0c = min(max(x0i, 0), W_ - 1), x1c = min(max(x1, 0), W_ - 1);
        int a00 = ((b * H_ + y0c) * W_ + x0c) * C_;
        int a01 = ((b * H_ + y0c) * W_ + x1c) * C_;
        int a10 = ((b * H_ + y1c) * W_ + x0c) * C_;
        int a11 = ((b * H_ + y1c) * W_ + x1c) * C_;
#pragma unroll
        for (int cc = 0; cc < 2; ++cc) {
            int ch = cc * 128 + j * 8;
            ushort8 v00 = *(const ushort8*)(XT + a00 + ch);
            ushort8 v01 = *(const ushort8*)(XT + a01 + ch);
            ushort8 v10 = *(const ushort8*)(XT + a10 + ch);
            ushort8 v11 = *(const ushort8*)(XT + a11 + ch);
            float v[8];
#pragma unroll
            for (int t = 0; t < 8; t++)
                v[t] = fw0 * b2f(v00[t]) + fw1 * b2f(v01[t])
                     + fw2 * b2f(v10[t]) + fw3 * b2f(v11[t]);
            uint4 sv;
            sv.x = pack2(v[0], v[1]);
            sv.y = pack2(v[2], v[3]);
            sv.z = pack2(v[4], v[5]);
            sv.w = pack2(v[6], v[7]);
            *(uint4*)&T[px][ch] = sv;
        }
        __syncthreads();
        // coalesced write: SQ chunk32 span for this block = 16px x 64B, contiguous
#pragma unroll
        for (int r = 0; r < 2; ++r) {
            int cg  = u_cg0 + r * 4;
            uint4 val = *(const uint4*)&T[wpx0][cg * 32 + kp0];
            size_t base = ((size_t)(tap * 8 + cg) * NPX_ + n_base + wpx0) * 32 + kp0;
            *(uint4*)(SQ + base) = val;
        }
        __syncthreads();
    }
}

// ---------------- kernel 4: GEMM out = relu(BN(W*SQ)) + x ----------------
// Barrier-free, LDS-free. Both operands fragment-ordered -> every b128 load
// is a coalesced 1KB wave transaction. Block 128o x 64px (4 waves, each
// 64o x 32px), depth-2 chunk64 register pipeline. Grid (288 n-tiles, 2 o).
__global__ __launch_bounds__(256, 2) void gemm_kernel(
    const float* __restrict__ x, const u16* __restrict__ SQ,
    const u16* __restrict__ WQ, const float* __restrict__ AB,
    float* __restrict__ out)
{
    const int tid = threadIdx.x;
    const int wave = tid >> 6;
    const int lane = tid & 63;
    const int quad = lane >> 4;
    const int l15  = lane & 15;

    const int n0 = blockIdx.x * 64;
    const int o0 = blockIdx.y * 128;
    const int wo = (wave >> 1) * 64;
    const int wp = (wave & 1) * 32;

    const u16* srow  = SQ + ((size_t)(n0 + wp + l15)) * 32 + quad * 8;
    const u16* wbase = WQ + ((size_t)(o0 + wo + l15)) * 32 + quad * 8;

    float4v acc[4][2];
#pragma unroll
    for (int i = 0; i < 4; i++)
#pragma unroll
        for (int j = 0; j < 2; j++)
            acc[i][j] = float4v{0.f, 0.f, 0.f, 0.f};

    short8v aA[2][4], aB[2][4];      // [ks][mt]
    short8v bA[2][2], bB[2][2];      // [ks][nt]

    auto load_a = [&](int ch64, short8v A[2][4]) {
#pragma unroll
        for (int ks = 0; ks < 2; ++ks) {
            const u16* p = wbase + (size_t)(ch64 * 2 + ks) * (256 * 32);
#pragma unroll
            for (int mt = 0; mt < 4; ++mt)
                A[ks][mt] = *(const short8v*)(p + mt * 16 * 32);
        }
    };
    auto load_b = [&](int ch64, short8v Bv[2][2]) {
#pragma unroll
        for (int ks = 0; ks < 2; ++ks) {
            const u16* p = srow + (size_t)(ch64 * 2 + ks) * NPX_ * 32;
#pragma unroll
            for (int nt = 0; nt < 2; ++nt)
                Bv[ks][nt] = *(const short8v*)(p + nt * 16 * 32);
        }
    };
    auto domfma = [&](short8v A[2][4], short8v Bv[2][2]) {
#pragma unroll
        for (int ks = 0; ks < 2; ++ks)
#pragma unroll
            for (int mt = 0; mt < 4; ++mt)
#pragma unroll
                for (int nt = 0; nt < 2; ++nt)
                    acc[mt][nt] = __builtin_amdgcn_mfma_f32_16x16x32_bf16(
                        A[ks][mt], Bv[ks][nt], acc[mt][nt], 0, 0, 0);
    };

    load_a(0, aA); load_b(0, bA);
    for (int ch = 0; ch < 36; ch += 2) {
        if (ch + 1 < 36) { load_a(ch + 1, aB); load_b(ch + 1, bB); }
        domfma(aA, bA);
        if (ch + 2 < 36) { load_a(ch + 2, aA); load_b(ch + 2, bA); }
        domfma(aB, bB);
    }

    // epilogue: BN fold + relu + residual
    const float* Ao = AB;
    const float* Bo = AB + 256;
    const int b    = n0 / HW_;           // 64-px block never straddles batch
    const int pix0 = n0 - b * HW_ + wp;
#pragma unroll
    for (int mt = 0; mt < 4; mt++) {
#pragma unroll
        for (int nt = 0; nt < 2; nt++) {
            int pix = pix0 + nt * 16 + l15;
#pragma unroll
            for (int r = 0; r < 4; r++) {
                int o = o0 + wo + mt * 16 + quad * 4 + r;
                float v = acc[mt][nt][r] * Ao[o] + Bo[o];
                v = fmaxf(v, 0.f);
                int gi = (b * C_ + o) * HW_ + pix;
                out[gi] = x[gi] + v;
            }
        }
    }
}

extern "C" void kernel_launch(void* const* d_in, const int* in_sizes, int n_in,
                              void* d_out, int out_size, void* d_ws, size_t ws_size,
                              hipStream_t stream)
{
    (void)in_sizes; (void)n_in; (void)out_size; (void)ws_size;
    const float* x      = (const float*)d_in[0];
    const float* w_off  = (const float*)d_in[1];
    const float* b_off  = (const float*)d_in[2];
    const float* w_conv = (const float*)d_in[3];
    const float* b_conv = (const float*)d_in[4];
    const float* gamma  = (const float*)d_in[5];
    const float* beta   = (const float*)d_in[6];
    const float* rmean  = (const float*)d_in[7];
    const float* rvar   = (const float*)d_in[8];
    float* out = (float*)d_out;

    float* ws = (float*)d_ws;
    float* AB = ws;                            // 512 floats
    u16* WQ = (u16*)(AB + 512);                // 589824
    u16* WO = WQ + 589824;                     // 73728
    u16* XT = WO + 73728;                      // 4718592
    u16* SQ = XT + 4718592;                    // 72*18432*32 = 42467328

    prep_w_kernel<<<2592, 256, 0, stream>>>(w_conv, w_off, b_conv, gamma, beta,
                                            rmean, rvar, AB, WQ, WO);
    xt_kernel<<<dim3(96, 16), 256, 0, stream>>>(x, XT);
    off_lerp_kernel<<<dim3(576, 2), 256, 0, stream>>>(XT, WO, b_off, SQ);
    gemm_kernel<<<dim3(288, 2), 256, 0, stream>>>(x, SQ, WQ, AB, out);
}

// Round 10
// 175.130 us; speedup vs baseline: 1.3929x; 1.2571x over previous
//
#include <hip/hip_runtime.h>
#include <hip/hip_bf16.h>

#define H_ 96
#define W_ 96
#define HW_ 9216
#define C_ 256
#define B_ 2
#define KO_ 27
#define NPX_ 18432   // B*HW
#define EPS_ 1e-5f

typedef unsigned short u16;
typedef unsigned short ushort8 __attribute__((ext_vector_type(8)));
typedef short short8v __attribute__((ext_vector_type(8)));
typedef float float4v __attribute__((ext_vector_type(4)));

__device__ __forceinline__ float b2f(u16 u) {
    return __uint_as_float(((unsigned int)u) << 16);
}
__device__ __forceinline__ u16 f2b(float f) {
    __hip_bfloat16 h = __float2bfloat16(f);
    union { __hip_bfloat16 h; u16 u; } cv; cv.h = h; return cv.u;
}
__device__ __forceinline__ unsigned int pack2(float a, float b) {
    union { __hip_bfloat162 h; unsigned int u; } cv;
    cv.h = __float22bfloat162_rn(make_float2(a, b));
    return cv.u;
}
// async global->LDS, 16B per lane; LDS dest = uniform base + lane*16
__device__ __forceinline__ void glds16(const u16* g, u16* l) {
    __builtin_amdgcn_global_load_lds(
        (const __attribute__((address_space(1))) void*)g,
        (__attribute__((address_space(3))) void*)l, 16, 0, 0);
}

// ---------------- kernel 1: weight repacks + BN fold -------
// WQ[((tap*8+cg)*256+o)*32+cp] = bf16(w_conv[o][c][tap]),  c = cg*32+cp
// WO[(tap*8+cg)*1024 + o*32 + cp] = bf16(w_off[o][c][tap]) (o<27, else 0)
__global__ __launch_bounds__(256) void prep_w_kernel(
    const float* __restrict__ w_conv, const float* __restrict__ w_off,
    const float* __restrict__ b_conv,
    const float* __restrict__ gamma, const float* __restrict__ beta,
    const float* __restrict__ rmean, const float* __restrict__ rvar,
    float* __restrict__ AB, u16* __restrict__ WQ, u16* __restrict__ WO)
{
    if (blockIdx.x == 0) {
        int o = threadIdx.x;
        float sc = gamma[o] * rsqrtf(rvar[o] + EPS_);
        AB[o] = sc;
        AB[256 + o] = beta[o] + (b_conv[o] - rmean[o]) * sc;
    }
    if (blockIdx.x < 2304) {
        int idx = blockIdx.x * 256 + threadIdx.x;   // 589824 total
        int ch = idx >> 13;          // chunk = tap*8 + c/32
        int o  = (idx >> 5) & 255;
        int cp = idx & 31;
        int c  = ((ch & 7) << 5) + cp;
        int k  = ch >> 3;
        WQ[idx] = f2b(w_conv[(o * C_ + c) * 9 + k]);
    } else {
        int j = (blockIdx.x - 2304) * 256 + threadIdx.x;  // 73728 total
        int ch = j >> 10;
        int o  = (j >> 5) & 31;
        int cp = j & 31;
        int c  = ((ch & 7) << 5) + cp;
        int k  = ch >> 3;
        WO[j] = (o < KO_) ? f2b(w_off[(o * C_ + c) * 9 + k]) : (u16)0;
    }
}

// ---------------- kernel 2: x NCHW f32 -> NHWC bf16 ----------------
__global__ __launch_bounds__(256) void xt_kernel(const float* __restrict__ x,
                                                 u16* __restrict__ XT)
{
    __shared__ u16 ls[32][100];
    int h  = blockIdx.x;
    int cg = blockIdx.y & 7;
    int b  = blockIdx.y >> 3;
    int c0 = cg * 32;
    for (int e = threadIdx.x; e < 32 * W_; e += 256) {
        int ci = e / W_, w = e % W_;
        ls[ci][w] = f2b(x[((b * C_ + c0 + ci) * H_ + h) * W_ + w]);
    }
    __syncthreads();
    for (int e = threadIdx.x; e < 32 * W_; e += 256) {
        int w = e >> 5, ci = e & 31;
        XT[((b * H_ + h) * W_ + w) * C_ + c0 + ci] = ls[ci][w];
    }
}

// ---------------- kernel 3: offsets (MFMA) + lerp -> SQ (fragment-ordered) --
// SQ[(ch32*NPX + n)*32 + kp] = lerped bf16 for channel c = (ch32&7)*32+kp,
// tap = ch32>>3, pixel n = b*HW + pix.
__global__ __launch_bounds__(256) void off_lerp_kernel(
    const u16* __restrict__ XT, const u16* __restrict__ WO,
    const float* __restrict__ b_off, u16* __restrict__ SQ)
{
    __shared__ float red[4][32][16];
    __shared__ float offv[27][16];
    __shared__ u16 T[16][264];          // [px][c] lerp tile for one tap

    const int tid = threadIdx.x;
    const int b  = blockIdx.y;
    const int p0 = blockIdx.x * 16;
    const int h  = p0 / W_;            // 16 px all on one row
    const int w0 = p0 % W_;

    const int wave = tid >> 6;
    const int lane = tid & 63;
    const int quad = lane >> 4;
    const int l15  = lane & 15;

    // ---- phase 1: 27x2304 offset GEMM, K split across 4 waves ----
    {
        const int pw = w0 + l15;
        float4v acc0 = float4v{0.f,0.f,0.f,0.f};
        float4v acc1 = float4v{0.f,0.f,0.f,0.f};
        int basec = 0; bool vld = true; int curtap = -1;
        auto set_tap = [&](int tap) {
            int py  = h + tap / 3 - 1;
            int pxl = pw + tap % 3 - 1;
            vld = ((unsigned)py < (unsigned)H_) && ((unsigned)pxl < (unsigned)W_);
            int pyc = min(max(py, 0), H_ - 1);
            int pxc = min(max(pxl, 0), W_ - 1);
            basec = ((b * H_ + pyc) * W_ + pxc) * C_ + quad * 8;
        };
        auto bload = [&](int c32) -> ushort8 {
            ushort8 v = *(const ushort8*)(XT + basec + (c32 & 7) * 32);
#pragma unroll
            for (int j = 0; j < 8; j++) v[j] = vld ? v[j] : (u16)0;
            return v;
        };
        const int c0 = wave * 18, c1 = c0 + 18;
        curtap = c0 >> 3;
        set_tap(curtap);
        ushort8 bq = bload(c0);
        short8v wa = *(const short8v*)(WO + c0 * 1024 + l15 * 32 + quad * 8);
        short8v wb = *(const short8v*)(WO + c0 * 1024 + l15 * 32 + quad * 8 + 512);
        for (int i = c0; i < c1; ++i) {
            ushort8 bc = bq;
            short8v wac = wa, wbc = wb;
            int nx = i + 1;
            if (nx < c1) {
                int t = nx >> 3;
                if (t != curtap) { set_tap(t); curtap = t; }
                bq = bload(nx);
                wa = *(const short8v*)(WO + nx * 1024 + l15 * 32 + quad * 8);
                wb = *(const short8v*)(WO + nx * 1024 + l15 * 32 + quad * 8 + 512);
            }
            union { ushort8 u; short8v s; } cb; cb.u = bc;
            acc0 = __builtin_amdgcn_mfma_f32_16x16x32_bf16(wac, cb.s, acc0, 0, 0, 0);
            acc1 = __builtin_amdgcn_mfma_f32_16x16x32_bf16(wbc, cb.s, acc1, 0, 0, 0);
        }
#pragma unroll
        for (int r = 0; r < 4; ++r) {
            red[wave][quad * 4 + r][l15]      = acc0[r];
            red[wave][16 + quad * 4 + r][l15] = acc1[r];
        }
    }
    __syncthreads();
#pragma unroll
    for (int rep = 0; rep < 2; ++rep) {
        int o  = (tid >> 4) + rep * 16;   // 0..31
        int px = tid & 15;
        if (o < KO_) {
            float v = red[0][o][px] + red[1][o][px] + red[2][o][px] + red[3][o][px]
                    + b_off[o];
            offv[o][px] = (o < 18) ? v : 1.f / (1.f + expf(-v));
        }
    }
    __syncthreads();

    // ---- phase 2: gather + lerp -> LDS tile -> coalesced SQ writes ----
    const int px = tid >> 4;      // 0..15
    const int j  = tid & 15;      // ch-lane
    const int pw2 = w0 + px;
    const int n_base = b * HW_ + p0;   // global n of px 0 in this block

    // write-phase mapping (2 units of 16B per thread per tap)
    const int u_cg0   = tid >> 6;            // r=0: cg 0..3
    const int u_in0   = tid & 63;
    const int wpx0    = u_in0 >> 2, kp0 = (u_in0 & 3) * 8;

    for (int tap = 0; tap < 9; ++tap) {
        float dy = offv[2 * tap][px];
        float dx = offv[2 * tap + 1][px];
        float m  = offv[18 + tap][px];
        float py  = (float)(h + tap / 3 - 1) + dy;
        float pxx = (float)(pw2 + tap % 3 - 1) + dx;
        float y0f = floorf(py), x0f = floorf(pxx);
        float ly = py - y0f, lx = pxx - x0f;
        int y0 = (int)y0f, x0i = (int)x0f;
        int y1 = y0 + 1, x1 = x0i + 1;
        bool vy0 = (unsigned)y0 < (unsigned)H_;
        bool vy1 = (unsigned)y1 < (unsigned)H_;
        bool vx0 = (unsigned)x0i < (unsigned)W_;
        bool vx1 = (unsigned)x1 < (unsigned)W_;
        float fw0 = (vy0 && vx0) ? (1.f - ly) * (1.f - lx) * m : 0.f;
        float fw1 = (vy0 && vx1) ? (1.f - ly) * lx * m : 0.f;
        float fw2 = (vy1 && vx0) ? ly * (1.f - lx) * m : 0.f;
        float fw3 = (vy1 && vx1) ? ly * lx * m : 0.f;
        int y0c = min(max(y0, 0), H_ - 1), y1c = min(max(y1, 0), H_ - 1);
        int x0c = min(max(x0i, 0), W_ - 1), x1c = min(max(x1, 0), W_ - 1);
        int a00 = ((b * H_ + y0c) * W_ + x0c) * C_;
        int a01 = ((b * H_ + y0c) * W_ + x1c) * C_;
        int a10 = ((b * H_ + y1c) * W_ + x0c) * C_;
        int a11 = ((b * H_ + y1c) * W_ + x1c) * C_;
#pragma unroll
        for (int cc = 0; cc < 2; ++cc) {
            int ch = cc * 128 + j * 8;
            ushort8 v00 = *(const ushort8*)(XT + a00 + ch);
            ushort8 v01 = *(const ushort8*)(XT + a01 + ch);
            ushort8 v10 = *(const ushort8*)(XT + a10 + ch);
            ushort8 v11 = *(const ushort8*)(XT + a11 + ch);
            float v[8];
#pragma unroll
            for (int t = 0; t < 8; t++)
                v[t] = fw0 * b2f(v00[t]) + fw1 * b2f(v01[t])
                     + fw2 * b2f(v10[t]) + fw3 * b2f(v11[t]);
            uint4 sv;
            sv.x = pack2(v[0], v[1]);
            sv.y = pack2(v[2], v[3]);
            sv.z = pack2(v[4], v[5]);
            sv.w = pack2(v[6], v[7]);
            *(uint4*)&T[px][ch] = sv;
        }
        __syncthreads();
        // coalesced write: SQ chunk32 span for this block = 16px x 64B, contiguous
#pragma unroll
        for (int r = 0; r < 2; ++r) {
            int cg  = u_cg0 + r * 4;
            uint4 val = *(const uint4*)&T[wpx0][cg * 32 + kp0];
            size_t base = ((size_t)(tap * 8 + cg) * NPX_ + n_base + wpx0) * 32 + kp0;
            *(uint4*)(SQ + base) = val;
        }
        __syncthreads();
    }
}

// ---------------- kernel 4: GEMM out = relu(BN(W*SQ)) + x ----------------
// m97 structure: global_load_lds (16B) staging into single 24KB LDS buffer,
// 2-barrier K-loop, ds_read_b128 fragments, MFMA. Block 128o x 64px, 4 waves
// (wave = 64o x 32px), K = 36 steps of 64. Grid (288 n-tiles, 2 o-halves).
__global__ __launch_bounds__(256) void gemm_kernel(
    const float* __restrict__ x, const u16* __restrict__ SQ,
    const u16* __restrict__ WQ, const float* __restrict__ AB,
    float* __restrict__ out)
{
    __shared__ __align__(16) u16 sA[2 * 128 * 32];   // 16 KB: [cc][o 128][kp 32]
    __shared__ __align__(16) u16 sB[2 * 64 * 32];    //  8 KB: [cc][n 64][kp 32]

    const int tid = threadIdx.x;
    const int wave = tid >> 6;
    const int lane = tid & 63;
    const int quad = lane >> 4;
    const int l15  = lane & 15;

    const int n0 = blockIdx.x * 64;
    const int o0 = blockIdx.y * 128;
    const int wo = (wave >> 1) * 64;
    const int wp = (wave & 1) * 32;

    float4v acc[4][2];
#pragma unroll
    for (int i = 0; i < 4; i++)
#pragma unroll
        for (int j = 0; j < 2; j++)
            acc[i][j] = float4v{0.f, 0.f, 0.f, 0.f};

    const int le8 = lane * 8;    // lane elem offset within a 1KB unit

    for (int ch = 0; ch < 36; ++ch) {
        // ---- stage K64: 16KB A (16 units) + 8KB B (8 units), 6 units/wave ----
#pragma unroll
        for (int i = 0; i < 4; ++i) {                 // A units
            int unit = wave + i * 4;                  // 0..15, wave-uniform
            int cc = unit >> 3;
            const u16* g = WQ + (size_t)(ch * 2 + cc) * 8192
                         + o0 * 32 + (unit & 7) * 512 + le8;
            glds16(g, &sA[unit * 512]);
        }
#pragma unroll
        for (int i = 0; i < 2; ++i) {                 // B units
            int u2 = wave + i * 4;                    // 0..7, wave-uniform
            int cc = u2 >> 2;
            const u16* g = SQ + ((size_t)(ch * 2 + cc) * NPX_ + n0) * 32
                         + (u2 & 3) * 512 + le8;
            glds16(g, &sB[u2 * 512]);
        }
        __syncthreads();   // drains vmcnt -> LDS tile complete

        // ---- compute ----
        short8v af[2][4], bf[2][2];
#pragma unroll
        for (int cc = 0; cc < 2; ++cc) {
#pragma unroll
            for (int mt = 0; mt < 4; ++mt)
                af[cc][mt] = *(const short8v*)
                    &sA[(cc * 128 + wo + mt * 16 + l15) * 32 + quad * 8];
#pragma unroll
            for (int nt = 0; nt < 2; ++nt)
                bf[cc][nt] = *(const short8v*)
                    &sB[(cc * 64 + wp + nt * 16 + l15) * 32 + quad * 8];
        }
#pragma unroll
        for (int cc = 0; cc < 2; ++cc)
#pragma unroll
            for (int mt = 0; mt < 4; ++mt)
#pragma unroll
                for (int nt = 0; nt < 2; ++nt)
                    acc[mt][nt] = __builtin_amdgcn_mfma_f32_16x16x32_bf16(
                        af[cc][mt], bf[cc][nt], acc[mt][nt], 0, 0, 0);
        __syncthreads();   // LDS reuse protection
    }

    // epilogue: BN fold + relu + residual
    const float* Ao = AB;
    const float* Bo = AB + 256;
    const int b    = n0 / HW_;           // 64-px block never straddles batch
    const int pix0 = n0 - b * HW_ + wp;
#pragma unroll
    for (int mt = 0; mt < 4; mt++) {
#pragma unroll
        for (int nt = 0; nt < 2; nt++) {
            int pix = pix0 + nt * 16 + l15;
#pragma unroll
            for (int r = 0; r < 4; r++) {
                int o = o0 + wo + mt * 16 + quad * 4 + r;
                float v = acc[mt][nt][r] * Ao[o] + Bo[o];
                v = fmaxf(v, 0.f);
                int gi = (b * C_ + o) * HW_ + pix;
                out[gi] = x[gi] + v;
            }
        }
    }
}

extern "C" void kernel_launch(void* const* d_in, const int* in_sizes, int n_in,
                              void* d_out, int out_size, void* d_ws, size_t ws_size,
                              hipStream_t stream)
{
    (void)in_sizes; (void)n_in; (void)out_size; (void)ws_size;
    const float* x      = (const float*)d_in[0];
    const float* w_off  = (const float*)d_in[1];
    const float* b_off  = (const float*)d_in[2];
    const float* w_conv = (const float*)d_in[3];
    const float* b_conv = (const float*)d_in[4];
    const float* gamma  = (const float*)d_in[5];
    const float* beta   = (const float*)d_in[6];
    const float* rmean  = (const float*)d_in[7];
    const float* rvar   = (const float*)d_in[8];
    float* out = (float*)d_out;

    float* ws = (float*)d_ws;
    float* AB = ws;                            // 512 floats
    u16* WQ = (u16*)(AB + 512);                // 589824
    u16* WO = WQ + 589824;                     // 73728
    u16* XT = WO + 73728;                      // 4718592
    u16* SQ = XT + 4718592;                    // 72*18432*32 = 42467328

    prep_w_kernel<<<2592, 256, 0, stream>>>(w_conv, w_off, b_conv, gamma, beta,
                                            rmean, rvar, AB, WQ, WO);
    xt_kernel<<<dim3(96, 16), 256, 0, stream>>>(x, XT);
    off_lerp_kernel<<<dim3(576, 2), 256, 0, stream>>>(XT, WO, b_off, SQ);
    gemm_kernel<<<dim3(288, 2), 256, 0, stream>>>(x, SQ, WQ, AB, out);
}